// Round 10
// baseline (511.854 us; speedup 1.0000x reference)
//
#include <hip/hip_runtime.h>
#include <math.h>

// Problem constants
#define S 64
#define F 10
#define K 7
#define D 512
#define HH 196   // H*H = 14*14
#define DT 128
#define NF (S*F)          // 640
#define NROWS_V (S*F*K)   // 4480
#define NROWS_A (S*K)     // 448
#define NOUT (S*K*F)      // 4480
#define MLP_R 8
#define NA_BLK (NROWS_A / MLP_R)   // 56
#define NV_BLK (NROWS_V / MLP_R)   // 560
#define WT 32                      // d-rows per staged W tile
#define WTILE_F4 (WT * DT / 4)     // 1024 float4 = 16 KB

// fg geometry
#define FG_TPB 256
#define FG_NT 16
#define FG_TILE_F4 784
#define FG_SLOTS 832

// Measurement reps (this round): surface fg and mlp2 above the ~147us poison
// fills so rocprof top-5 shows their counters. zoff==0 at runtime (opaque to
// compiler). Deterministic: every rep recomputes identical values.
#define FG_REPS 4
#define MLP_REPS 10

// ---------------------------------------------------------------------------
// Kernel 1 (v7, R8-validated): fg = einsum/camsum. cam slice in registers,
// contiguous global_load_lds staging, double-buffered. ~45 us/rep measured.
// ---------------------------------------------------------------------------
__device__ __forceinline__ void fg_stage(const float* region, float4* dst,
                                         int wave, int lane) {
#pragma unroll
  for (int i = wave; i < 13; i += 4) {
    const int p = i * 64 + lane;
    const int ps = (p < FG_TILE_F4) ? p : 0;
    __builtin_amdgcn_global_load_lds(
        (const __attribute__((address_space(1))) void*)(region + (size_t)ps * 4),
        (__attribute__((address_space(3))) void*)(dst + i * 64), 16, 0, 0);
  }
}

__global__ __launch_bounds__(FG_TPB) void fg_kernel(
    const float* __restrict__ feat, const float* __restrict__ cam,
    float* __restrict__ fg, int reps, size_t zoff) {
  __shared__ float4 buf[2][FG_SLOTS];
  __shared__ float inv_lds[K];

  const int t = threadIdx.x;
  const int lane = t & 63;
  const int wave = t >> 6;
  const int n = blockIdx.x >> 1;
  const int half = blockIdx.x & 1;
  const int c0blk = half * 256;
  const int cl = t >> 4;
  const int s16 = t & 15;

  for (int r = 0; r < reps; ++r) {
    const float* featn = feat + r * zoff + ((size_t)n * D + c0blk) * HH;
    const float* camn = cam + r * zoff + (size_t)n * K * HH;
    const float4* camf4 = reinterpret_cast<const float4*>(camn);

    float4 cq0[K], cq1[K], cq2[K], cq3[K];
#pragma unroll
    for (int k = 0; k < K; ++k) {
      cq0[k] = camf4[k * 49 + s16];
      cq1[k] = camf4[k * 49 + 16 + s16];
      cq2[k] = camf4[k * 49 + 32 + s16];
      cq3[k] = (s16 == 0) ? camf4[k * 49 + 48] : make_float4(0.f, 0.f, 0.f, 0.f);
    }

    if (t < 64) {
      const bool act = lane < 49;
#pragma unroll
      for (int k = 0; k < K; ++k) {
        float4 cv = act ? camf4[k * 49 + lane] : make_float4(0.f, 0.f, 0.f, 0.f);
        float s = cv.x + cv.y + cv.z + cv.w;
#pragma unroll
        for (int m = 32; m >= 1; m >>= 1) s += __shfl_xor(s, m, 64);
        if (lane == 0) inv_lds[k] = 1.0f / (s + 1e-10f);
      }
    }

    fg_stage(featn, &buf[0][0], wave, lane);
    __syncthreads();

    float invr[K];
#pragma unroll
    for (int k = 0; k < K; ++k) invr[k] = inv_lds[k];

    float* fgn = fg + (size_t)n * K * D;

    for (int tt = 0; tt < FG_NT; ++tt) {
      const int cur = tt & 1;
      if (tt < FG_NT - 1)
        fg_stage(featn + (size_t)(tt + 1) * FG_TILE_F4 * 4,
                 &buf[cur ^ 1][0], wave, lane);

      const float4* tb = &buf[cur][0] + cl * 49;
      const float4 f0 = tb[s16];
      const float4 f1 = tb[16 + s16];
      const float4 f2 = tb[32 + s16];
      const float4 f3 = (s16 == 0) ? tb[48] : make_float4(0.f, 0.f, 0.f, 0.f);

      float acc[K];
#pragma unroll
      for (int k = 0; k < K; ++k) {
        float a = 0.f;
        a = fmaf(f0.x, cq0[k].x, a); a = fmaf(f0.y, cq0[k].y, a);
        a = fmaf(f0.z, cq0[k].z, a); a = fmaf(f0.w, cq0[k].w, a);
        a = fmaf(f1.x, cq1[k].x, a); a = fmaf(f1.y, cq1[k].y, a);
        a = fmaf(f1.z, cq1[k].z, a); a = fmaf(f1.w, cq1[k].w, a);
        a = fmaf(f2.x, cq2[k].x, a); a = fmaf(f2.y, cq2[k].y, a);
        a = fmaf(f2.z, cq2[k].z, a); a = fmaf(f2.w, cq2[k].w, a);
        a = fmaf(f3.x, cq3[k].x, a); a = fmaf(f3.y, cq3[k].y, a);
        a = fmaf(f3.z, cq3[k].z, a); a = fmaf(f3.w, cq3[k].w, a);
        acc[k] = a;
      }
#pragma unroll
      for (int m = 1; m <= 8; m <<= 1) {
#pragma unroll
        for (int k = 0; k < K; ++k) acc[k] += __shfl_xor(acc[k], m, 64);
      }
      if (s16 == 0) {
        const int c = c0blk + tt * 16 + cl;
#pragma unroll
        for (int k = 0; k < K; ++k) fgn[k * D + c] = acc[k] * invr[k];
      }
      __syncthreads();
    }
    __syncthreads();  // rep boundary: inv_lds rewrite guard
  }
}

// ---------------------------------------------------------------------------
// Kernel 2 (v5): BOTH MLPs. 8 rows/block x 256 thr (thread = 1 row x 4 cols)
// -> 616 blocks (2.4/CU). LDS = W double-buffer (32 KB) + hs (4 KB) = 36 KB
// -> 3-4 blocks/CU co-resident: cross-block overlap hides stage/barrier
// stalls. x read straight from global (32-lane same-address -> L1 broadcast,
// each value used once).
// ---------------------------------------------------------------------------
__device__ __forceinline__ void fma4(float4& acc, float sx, const float4& wv) {
  acc.x += sx * wv.x; acc.y += sx * wv.y; acc.z += sx * wv.z; acc.w += sx * wv.w;
}

__device__ __forceinline__ void stage_w(const float* src, float4* dst, int t) {
#pragma unroll
  for (int i = 0; i < WTILE_F4; i += 256) {
    __builtin_amdgcn_global_load_lds(
        (const __attribute__((address_space(1))) void*)(src + (size_t)(i + t) * 4),
        (__attribute__((address_space(3))) void*)(dst + i + t), 16, 0, 0);
  }
}

__global__ __launch_bounds__(256) void mlp2_kernel(
    const float* __restrict__ Xa, const float* __restrict__ Xv,
    const float* __restrict__ W1a, const float* __restrict__ b1a,
    const float* __restrict__ W2a, const float* __restrict__ b2a,
    const float* __restrict__ ga, const float* __restrict__ bna,
    const float* __restrict__ W1v, const float* __restrict__ b1v,
    const float* __restrict__ W2v, const float* __restrict__ b2v,
    const float* __restrict__ gv, const float* __restrict__ bnv,
    float* __restrict__ Ta, float* __restrict__ Tv, int reps, size_t zoff) {
  __shared__ float4 wbuf[2][WTILE_F4];   // 32 KB
  __shared__ float hs[MLP_R * DT];       // 4 KB
  const int t = threadIdx.x;
  const int b = blockIdx.x;

  const float *X0, *W10, *b1, *W20, *b2, *g, *bn;
  float* out;
  int r0;
  if (b < NA_BLK) {
    X0 = Xa; W10 = W1a; b1 = b1a; W20 = W2a; b2 = b2a; g = ga; bn = bna;
    out = Ta; r0 = b * MLP_R;
  } else {
    X0 = Xv; W10 = W1v; b1 = b1v; W20 = W2v; b2 = b2v; g = gv; bn = bnv;
    out = Tv; r0 = (b - NA_BLK) * MLP_R;
  }

  const int cg = t & 31;   // col group -> j0 = cg*4
  const int j0 = cg * 4;
  const int rp = t >> 5;   // row 0..7

  for (int r = 0; r < reps; ++r) {
    const float* X = X0 + r * zoff;
    const float* W1 = W10 + r * zoff;
    const float* W2 = W20 + r * zoff;
    const float4* xrow = reinterpret_cast<const float4*>(X + (size_t)(r0 + rp) * D);

    stage_w(W1, &wbuf[0][0], t);
    __syncthreads();  // W1 tile 0 landed

    // ---- layer 1: 16 tiles of 32 d-rows ----
    float4 a0 = *reinterpret_cast<const float4*>(b1 + j0);
    for (int dt = 0; dt < 16; ++dt) {
      if (dt < 15) stage_w(W1 + (size_t)(dt + 1) * WT * DT, &wbuf[(dt + 1) & 1][0], t);
      else         stage_w(W2, &wbuf[0][0], t);  // prefetch W2 tile 0
      const float4* wb = &wbuf[dt & 1][0];
#pragma unroll
      for (int d4 = 0; d4 < 8; ++d4) {
        const float4 x0 = xrow[dt * 8 + d4];
        const float4 w0 = wb[(d4 * 4 + 0) * 32 + cg];
        const float4 w1 = wb[(d4 * 4 + 1) * 32 + cg];
        const float4 w2 = wb[(d4 * 4 + 2) * 32 + cg];
        const float4 w3 = wb[(d4 * 4 + 3) * 32 + cg];
        fma4(a0, x0.x, w0); fma4(a0, x0.y, w1); fma4(a0, x0.z, w2); fma4(a0, x0.w, w3);
      }
      __syncthreads();  // stage landed; all waves done with wbuf[dt&1]
    }

    // relu -> hs
    a0.x = fmaxf(a0.x, 0.f); a0.y = fmaxf(a0.y, 0.f);
    a0.z = fmaxf(a0.z, 0.f); a0.w = fmaxf(a0.w, 0.f);
    *reinterpret_cast<float4*>(hs + rp * DT + j0) = a0;
    __syncthreads();  // hs published (W2 tile 0 landed at loop-end barrier)

    const float4* hrow = reinterpret_cast<const float4*>(hs + rp * DT);

    // ---- layer 2: 4 tiles ----
    float4 c0 = *reinterpret_cast<const float4*>(b2 + j0);
    for (int dt = 0; dt < 4; ++dt) {
      if (dt < 3) stage_w(W2 + (size_t)(dt + 1) * WT * DT, &wbuf[(dt + 1) & 1][0], t);
      const float4* wb = &wbuf[dt & 1][0];
#pragma unroll
      for (int d4 = 0; d4 < 8; ++d4) {
        const float4 x0 = hrow[dt * 8 + d4];
        const float4 w0 = wb[(d4 * 4 + 0) * 32 + cg];
        const float4 w1 = wb[(d4 * 4 + 1) * 32 + cg];
        const float4 w2 = wb[(d4 * 4 + 2) * 32 + cg];
        const float4 w3 = wb[(d4 * 4 + 3) * 32 + cg];
        fma4(c0, x0.x, w0); fma4(c0, x0.y, w1); fma4(c0, x0.z, w2); fma4(c0, x0.w, w3);
      }
      __syncthreads();
    }

    // affine epilogue
    const float4 gvv = *reinterpret_cast<const float4*>(g + j0);
    const float4 bv = *reinterpret_cast<const float4*>(bn + j0);
    float4 o0;
    o0.x = c0.x * gvv.x + bv.x; o0.y = c0.y * gvv.y + bv.y;
    o0.z = c0.z * gvv.z + bv.z; o0.w = c0.w * gvv.w + bv.w;
    *reinterpret_cast<float4*>(out + (size_t)(r0 + rp) * DT + j0) = o0;
    __syncthreads();  // rep boundary guard
  }
}

// ---------------------------------------------------------------------------
// Kernel 3: losses + masks (unchanged; ~0.85 us measured).
// ---------------------------------------------------------------------------
__global__ __launch_bounds__(256) void loss_kernel(
    const float* __restrict__ Ta, const float* __restrict__ Tv,
    const float* __restrict__ pred_a, const float* __restrict__ pred_v,
    const int* __restrict__ perm_idx, const int* __restrict__ cls_idx,
    float* __restrict__ out) {
  const int t = threadIdx.x;
  const int sub = t & 31;
  const int idx = blockIdx.x * 8 + (t >> 5);
  const int f = idx % F;
  const int k = (idx / F) % K;
  const int s = idx / (K * F);

  const int p = perm_idx[idx];
  const int c = cls_idx[idx];
  const int rowd = ((s ^ 1) * F + p) * K + c;

  float4 ta = reinterpret_cast<const float4*>(Ta)[(s * K + k) * 32 + sub];
  float4 tv = reinterpret_cast<const float4*>(Tv)[((s * F + f) * K + k) * 32 + sub];
  float4 td = reinterpret_cast<const float4*>(Tv)[rowd * 32 + sub];
  float d1 = 0.f, d2 = 0.f, e;
  e = ta.x - tv.x; d1 += e * e;
  e = ta.y - tv.y; d1 += e * e;
  e = ta.z - tv.z; d1 += e * e;
  e = ta.w - tv.w; d1 += e * e;
  e = ta.x - td.x; d2 += e * e;
  e = ta.y - td.y; d2 += e * e;
  e = ta.z - td.z; d2 += e * e;
  e = ta.w - td.w; d2 += e * e;
#pragma unroll
  for (int m = 16; m >= 1; m >>= 1) {
    d1 += __shfl_xor(d1, m, 64);
    d2 += __shfl_xor(d2, m, 64);
  }
  if (sub == 0) {
    float pa = pred_a[s * K + k];
    bool act = pa > 0.3f;
    int num = (int)floorf(pa * (float)F);
    float pvv = pred_v[(s * F + f) * K + k];
    float sg = 1.0f / (1.0f + expf(-pvv));
    bool mco = act && (sg > 0.3f);
    bool mdi = act && (f < num);
    float lco = d1 * (1.0f / 128.0f);
    float ldi = d2 * (1.0f / 128.0f);
    out[idx] = mco ? lco : 0.0f;
    out[NOUT + idx] = mdi ? ldi : 0.0f;
    out[2 * NOUT + idx] = mco ? 1.0f : 0.0f;
    out[3 * NOUT + idx] = mdi ? 1.0f : 0.0f;
  }
}

extern "C" void kernel_launch(void* const* d_in, const int* in_sizes, int n_in,
                              void* d_out, int out_size, void* d_ws, size_t ws_size,
                              hipStream_t stream) {
  const float* feat_a     = (const float*)d_in[0];
  const float* pred_a     = (const float*)d_in[1];
  const float* feat_v_raw = (const float*)d_in[2];
  const float* pred_v     = (const float*)d_in[3];
  const float* cam        = (const float*)d_in[4];
  const float* W1a = (const float*)d_in[5];
  const float* b1a = (const float*)d_in[6];
  const float* W2a = (const float*)d_in[7];
  const float* b2a = (const float*)d_in[8];
  const float* ga  = (const float*)d_in[9];
  const float* bna = (const float*)d_in[10];
  const float* W1v = (const float*)d_in[11];
  const float* b1v = (const float*)d_in[12];
  const float* W2v = (const float*)d_in[13];
  const float* b2v = (const float*)d_in[14];
  const float* gv  = (const float*)d_in[15];
  const float* bnv = (const float*)d_in[16];
  const int* perm_idx = (const int*)d_in[17];
  const int* cls_idx  = (const int*)d_in[18];
  float* out = (float*)d_out;

  // workspace layout (floats): fg[640*7*512] | Ta[448*128] | Tv[4480*128]
  float* ws = (float*)d_ws;
  float* fg = ws;
  float* Ta = fg + (size_t)NF * K * D;
  float* Tv = Ta + (size_t)NROWS_A * DT;

  fg_kernel<<<NF * 2, FG_TPB, 0, stream>>>(feat_v_raw, cam, fg, FG_REPS, (size_t)0);
  mlp2_kernel<<<NA_BLK + NV_BLK, 256, 0, stream>>>(
      feat_a, fg, W1a, b1a, W2a, b2a, ga, bna,
      W1v, b1v, W2v, b2v, gv, bnv, Ta, Tv, MLP_REPS, (size_t)0);
  loss_kernel<<<NOUT / 8, 256, 0, stream>>>(Ta, Tv, pred_a, pred_v, perm_idx,
                                            cls_idx, out);
}

// Round 11
// 85.153 us; speedup vs baseline: 6.0110x; 6.0110x over previous
//
#include <hip/hip_runtime.h>
#include <math.h>

// Problem constants
#define S 64
#define F 10
#define K 7
#define D 512
#define HH 196   // H*H = 14*14
#define DT 128
#define NF (S*F)          // 640
#define NROWS_V (S*F*K)   // 4480
#define NROWS_A (S*K)     // 448
#define NOUT (S*K*F)      // 4480
#define MLP_R 8
#define NA_BLK (NROWS_A / MLP_R)   // 56
#define NV_BLK (NROWS_V / MLP_R)   // 560
#define WT 32                      // d-rows per staged W tile
#define WTILE_F4 (WT * DT / 4)     // 1024 float4 = 16 KB

typedef short bf16x8 __attribute__((ext_vector_type(8)));
typedef float f32x4 __attribute__((ext_vector_type(4)));

// f32 -> bf16 bits, round-to-nearest-even
__device__ __forceinline__ short bfr(float x) {
  unsigned u = __float_as_uint(x);
  return (short)((u + 0x7fffu + ((u >> 16) & 1u)) >> 16);
}

// ---------------------------------------------------------------------------
// Kernel 1 (v8, MFMA): per n: C[512x7] = feat[512x196] x cam^T[196x7] via
// mfma_f32_16x16x32_bf16 (K padded to 224 = 7 slabs, N padded to 16).
// A and B fragments use the SAME elem->k convention (elem j <-> hw =
// slab*32 + (lane>>4)*8 + j), so correctness is independent of the
// instruction's internal k mapping. C/D: col=lane&15 (class), row =
// (lane>>4)*4+i (channel) [m89-verified].
// 1280 blocks (n x 256-ch half) x 4 independent waves; wave w owns m-tiles
// 4w..4w+3 (16 ch each). No LDS, no barriers, no shuffles in the hot loop;
// 14 independent 16B loads per m-tile keep HBM fed. bf16 inputs / f32
// accumulate: fg error ~1e-4, threshold 2e-2.
// ---------------------------------------------------------------------------
__global__ __launch_bounds__(256) void fg_kernel(
    const float* __restrict__ feat, const float* __restrict__ cam,
    float* __restrict__ fg) {
  const int t = threadIdx.x;
  const int lane = t & 63;
  const int w = t >> 6;        // wave 0..3
  const int col = lane & 15;   // class col (valid < 7)
  const int kg = lane >> 4;    // k-group 0..3
  const int n = blockIdx.x >> 1;
  const int half = blockIdx.x & 1;
  const int c0blk = half * 256;

  const float* featn = feat + ((size_t)n * D + c0blk) * HH;
  const float* camn = cam + (size_t)n * K * HH;

  // ---- B fragments (cam, bf16) for 7 k-slabs: 28 VGPR, built once ----
  bf16x8 bs[7];
  {
    const float* crow = camn + col * HH;
#pragma unroll
    for (int s = 0; s < 7; ++s) {
      float v0 = 0.f, v1 = 0.f, v2 = 0.f, v3 = 0.f;
      float v4 = 0.f, v5 = 0.f, v6 = 0.f, v7 = 0.f;
      if (col < 7) {
        if (s < 6) {
          const float4 lo = *reinterpret_cast<const float4*>(crow + s * 32 + kg * 8);
          const float4 hi = *reinterpret_cast<const float4*>(crow + s * 32 + kg * 8 + 4);
          v0 = lo.x; v1 = lo.y; v2 = lo.z; v3 = lo.w;
          v4 = hi.x; v5 = hi.y; v6 = hi.z; v7 = hi.w;
        } else if (kg == 0) {  // hw 192..195 valid, 196..199 padded 0
          const float4 lo = *reinterpret_cast<const float4*>(crow + 192);
          v0 = lo.x; v1 = lo.y; v2 = lo.z; v3 = lo.w;
        }
      }
      bs[s][0] = bfr(v0); bs[s][1] = bfr(v1); bs[s][2] = bfr(v2); bs[s][3] = bfr(v3);
      bs[s][4] = bfr(v4); bs[s][5] = bfr(v5); bs[s][6] = bfr(v6); bs[s][7] = bfr(v7);
    }
  }

  // ---- inv[col] via per-wave butterflies (no LDS, no barrier) ----
  float invc = 0.f;
#pragma unroll
  for (int k = 0; k < K; ++k) {
    float4 cv = (lane < 49)
                    ? *reinterpret_cast<const float4*>(camn + k * HH + 4 * lane)
                    : make_float4(0.f, 0.f, 0.f, 0.f);
    float s = cv.x + cv.y + cv.z + cv.w;
#pragma unroll
    for (int m = 32; m >= 1; m >>= 1) s += __shfl_xor(s, m, 64);
    const float iv = 1.0f / (s + 1e-10f);
    if (col == k) invc = iv;
  }

  float* fgn = fg + (size_t)n * K * D;

  // ---- 4 m-tiles of 16 channels each ----
#pragma unroll
  for (int mt = 0; mt < 4; ++mt) {
    const int chl = (w * 4 + mt) * 16 + col;  // channel-in-half for A row
    const float* rowp = featn + (size_t)chl * HH;

    f32x4 acc = {0.f, 0.f, 0.f, 0.f};
#pragma unroll
    for (int s = 0; s < 7; ++s) {
      float v0 = 0.f, v1 = 0.f, v2 = 0.f, v3 = 0.f;
      float v4 = 0.f, v5 = 0.f, v6 = 0.f, v7 = 0.f;
      if (s < 6) {
        const float4 lo = *reinterpret_cast<const float4*>(rowp + s * 32 + kg * 8);
        const float4 hi = *reinterpret_cast<const float4*>(rowp + s * 32 + kg * 8 + 4);
        v0 = lo.x; v1 = lo.y; v2 = lo.z; v3 = lo.w;
        v4 = hi.x; v5 = hi.y; v6 = hi.z; v7 = hi.w;
      } else if (kg == 0) {
        const float4 lo = *reinterpret_cast<const float4*>(rowp + 192);
        v0 = lo.x; v1 = lo.y; v2 = lo.z; v3 = lo.w;
      }
      bf16x8 a;
      a[0] = bfr(v0); a[1] = bfr(v1); a[2] = bfr(v2); a[3] = bfr(v3);
      a[4] = bfr(v4); a[5] = bfr(v5); a[6] = bfr(v6); a[7] = bfr(v7);
      acc = __builtin_amdgcn_mfma_f32_16x16x32_bf16(a, bs[s], acc, 0, 0, 0);
    }

    if (col < 7) {
      float4 o;
      o.x = acc[0] * invc; o.y = acc[1] * invc;
      o.z = acc[2] * invc; o.w = acc[3] * invc;
      *reinterpret_cast<float4*>(
          fgn + (size_t)col * D + c0blk + (w * 4 + mt) * 16 + kg * 4) = o;
    }
  }
}

// ---------------------------------------------------------------------------
// Kernel 2 (v5, R10-validated ~15-19 us): BOTH MLPs. 8 rows/block x 256 thr,
// W double-buffered through LDS via global_load_lds; x from global (L1
// broadcast). 616 blocks.
// ---------------------------------------------------------------------------
__device__ __forceinline__ void fma4(float4& acc, float sx, const float4& wv) {
  acc.x += sx * wv.x; acc.y += sx * wv.y; acc.z += sx * wv.z; acc.w += sx * wv.w;
}

__device__ __forceinline__ void stage_w(const float* src, float4* dst, int t) {
#pragma unroll
  for (int i = 0; i < WTILE_F4; i += 256) {
    __builtin_amdgcn_global_load_lds(
        (const __attribute__((address_space(1))) void*)(src + (size_t)(i + t) * 4),
        (__attribute__((address_space(3))) void*)(dst + i + t), 16, 0, 0);
  }
}

__global__ __launch_bounds__(256) void mlp2_kernel(
    const float* __restrict__ Xa, const float* __restrict__ Xv,
    const float* __restrict__ W1a, const float* __restrict__ b1a,
    const float* __restrict__ W2a, const float* __restrict__ b2a,
    const float* __restrict__ ga, const float* __restrict__ bna,
    const float* __restrict__ W1v, const float* __restrict__ b1v,
    const float* __restrict__ W2v, const float* __restrict__ b2v,
    const float* __restrict__ gv, const float* __restrict__ bnv,
    float* __restrict__ Ta, float* __restrict__ Tv) {
  __shared__ float4 wbuf[2][WTILE_F4];   // 32 KB
  __shared__ float hs[MLP_R * DT];       // 4 KB
  const int t = threadIdx.x;
  const int b = blockIdx.x;

  const float *X, *W1, *b1, *W2, *b2, *g, *bn;
  float* out;
  int r0;
  if (b < NA_BLK) {
    X = Xa; W1 = W1a; b1 = b1a; W2 = W2a; b2 = b2a; g = ga; bn = bna;
    out = Ta; r0 = b * MLP_R;
  } else {
    X = Xv; W1 = W1v; b1 = b1v; W2 = W2v; b2 = b2v; g = gv; bn = bnv;
    out = Tv; r0 = (b - NA_BLK) * MLP_R;
  }

  const int cg = t & 31;
  const int j0 = cg * 4;
  const int rp = t >> 5;
  const float4* xrow = reinterpret_cast<const float4*>(X + (size_t)(r0 + rp) * D);

  stage_w(W1, &wbuf[0][0], t);
  __syncthreads();

  // ---- layer 1: 16 tiles of 32 d-rows ----
  float4 a0 = *reinterpret_cast<const float4*>(b1 + j0);
  for (int dt = 0; dt < 16; ++dt) {
    if (dt < 15) stage_w(W1 + (size_t)(dt + 1) * WT * DT, &wbuf[(dt + 1) & 1][0], t);
    else         stage_w(W2, &wbuf[0][0], t);  // prefetch W2 tile 0
    const float4* wb = &wbuf[dt & 1][0];
#pragma unroll
    for (int d4 = 0; d4 < 8; ++d4) {
      const float4 x0 = xrow[dt * 8 + d4];
      const float4 w0 = wb[(d4 * 4 + 0) * 32 + cg];
      const float4 w1 = wb[(d4 * 4 + 1) * 32 + cg];
      const float4 w2 = wb[(d4 * 4 + 2) * 32 + cg];
      const float4 w3 = wb[(d4 * 4 + 3) * 32 + cg];
      fma4(a0, x0.x, w0); fma4(a0, x0.y, w1); fma4(a0, x0.z, w2); fma4(a0, x0.w, w3);
    }
    __syncthreads();
  }

  a0.x = fmaxf(a0.x, 0.f); a0.y = fmaxf(a0.y, 0.f);
  a0.z = fmaxf(a0.z, 0.f); a0.w = fmaxf(a0.w, 0.f);
  *reinterpret_cast<float4*>(hs + rp * DT + j0) = a0;
  __syncthreads();

  const float4* hrow = reinterpret_cast<const float4*>(hs + rp * DT);

  // ---- layer 2: 4 tiles ----
  float4 c0 = *reinterpret_cast<const float4*>(b2 + j0);
  for (int dt = 0; dt < 4; ++dt) {
    if (dt < 3) stage_w(W2 + (size_t)(dt + 1) * WT * DT, &wbuf[(dt + 1) & 1][0], t);
    const float4* wb = &wbuf[dt & 1][0];
#pragma unroll
    for (int d4 = 0; d4 < 8; ++d4) {
      const float4 x0 = hrow[dt * 8 + d4];
      const float4 w0 = wb[(d4 * 4 + 0) * 32 + cg];
      const float4 w1 = wb[(d4 * 4 + 1) * 32 + cg];
      const float4 w2 = wb[(d4 * 4 + 2) * 32 + cg];
      const float4 w3 = wb[(d4 * 4 + 3) * 32 + cg];
      fma4(c0, x0.x, w0); fma4(c0, x0.y, w1); fma4(c0, x0.z, w2); fma4(c0, x0.w, w3);
    }
    __syncthreads();
  }

  const float4 gvv = *reinterpret_cast<const float4*>(g + j0);
  const float4 bv = *reinterpret_cast<const float4*>(bn + j0);
  float4 o0;
  o0.x = c0.x * gvv.x + bv.x; o0.y = c0.y * gvv.y + bv.y;
  o0.z = c0.z * gvv.z + bv.z; o0.w = c0.w * gvv.w + bv.w;
  *reinterpret_cast<float4*>(out + (size_t)(r0 + rp) * DT + j0) = o0;
}

// ---------------------------------------------------------------------------
// Kernel 3: losses + masks (unchanged; ~0.85 us measured).
// ---------------------------------------------------------------------------
__global__ __launch_bounds__(256) void loss_kernel(
    const float* __restrict__ Ta, const float* __restrict__ Tv,
    const float* __restrict__ pred_a, const float* __restrict__ pred_v,
    const int* __restrict__ perm_idx, const int* __restrict__ cls_idx,
    float* __restrict__ out) {
  const int t = threadIdx.x;
  const int sub = t & 31;
  const int idx = blockIdx.x * 8 + (t >> 5);
  const int f = idx % F;
  const int k = (idx / F) % K;
  const int s = idx / (K * F);

  const int p = perm_idx[idx];
  const int c = cls_idx[idx];
  const int rowd = ((s ^ 1) * F + p) * K + c;

  float4 ta = reinterpret_cast<const float4*>(Ta)[(s * K + k) * 32 + sub];
  float4 tv = reinterpret_cast<const float4*>(Tv)[((s * F + f) * K + k) * 32 + sub];
  float4 td = reinterpret_cast<const float4*>(Tv)[rowd * 32 + sub];
  float d1 = 0.f, d2 = 0.f, e;
  e = ta.x - tv.x; d1 += e * e;
  e = ta.y - tv.y; d1 += e * e;
  e = ta.z - tv.z; d1 += e * e;
  e = ta.w - tv.w; d1 += e * e;
  e = ta.x - td.x; d2 += e * e;
  e = ta.y - td.y; d2 += e * e;
  e = ta.z - td.z; d2 += e * e;
  e = ta.w - td.w; d2 += e * e;
#pragma unroll
  for (int m = 16; m >= 1; m >>= 1) {
    d1 += __shfl_xor(d1, m, 64);
    d2 += __shfl_xor(d2, m, 64);
  }
  if (sub == 0) {
    float pa = pred_a[s * K + k];
    bool act = pa > 0.3f;
    int num = (int)floorf(pa * (float)F);
    float pvv = pred_v[(s * F + f) * K + k];
    float sg = 1.0f / (1.0f + expf(-pvv));
    bool mco = act && (sg > 0.3f);
    bool mdi = act && (f < num);
    float lco = d1 * (1.0f / 128.0f);
    float ldi = d2 * (1.0f / 128.0f);
    out[idx] = mco ? lco : 0.0f;
    out[NOUT + idx] = mdi ? ldi : 0.0f;
    out[2 * NOUT + idx] = mco ? 1.0f : 0.0f;
    out[3 * NOUT + idx] = mdi ? 1.0f : 0.0f;
  }
}

extern "C" void kernel_launch(void* const* d_in, const int* in_sizes, int n_in,
                              void* d_out, int out_size, void* d_ws, size_t ws_size,
                              hipStream_t stream) {
  const float* feat_a     = (const float*)d_in[0];
  const float* pred_a     = (const float*)d_in[1];
  const float* feat_v_raw = (const float*)d_in[2];
  const float* pred_v     = (const float*)d_in[3];
  const float* cam        = (const float*)d_in[4];
  const float* W1a = (const float*)d_in[5];
  const float* b1a = (const float*)d_in[6];
  const float* W2a = (const float*)d_in[7];
  const float* b2a = (const float*)d_in[8];
  const float* ga  = (const float*)d_in[9];
  const float* bna = (const float*)d_in[10];
  const float* W1v = (const float*)d_in[11];
  const float* b1v = (const float*)d_in[12];
  const float* W2v = (const float*)d_in[13];
  const float* b2v = (const float*)d_in[14];
  const float* gv  = (const float*)d_in[15];
  const float* bnv = (const float*)d_in[16];
  const int* perm_idx = (const int*)d_in[17];
  const int* cls_idx  = (const int*)d_in[18];
  float* out = (float*)d_out;

  // workspace layout (floats): fg[640*7*512] | Ta[448*128] | Tv[4480*128]
  float* ws = (float*)d_ws;
  float* fg = ws;
  float* Ta = fg + (size_t)NF * K * D;
  float* Tv = Ta + (size_t)NROWS_A * DT;

  fg_kernel<<<NF * 2, 256, 0, stream>>>(feat_v_raw, cam, fg);
  mlp2_kernel<<<NA_BLK + NV_BLK, 256, 0, stream>>>(
      feat_a, fg, W1a, b1a, W2a, b2a, ga, bna,
      W1v, b1v, W2v, b2v, gv, bnv, Ta, Tv);
  loss_kernel<<<NOUT / 8, 256, 0, stream>>>(Ta, Tv, pred_a, pred_v, perm_idx,
                                            cls_idx, out);
}